// Round 1
// baseline (226.262 us; speedup 1.0000x reference)
//
#include <hip/hip_runtime.h>

// B=32, D=128, K=32, N=9216. Fused softmax(scaled-L2)+aggregation, bf16 MFMA.
// Deterministic: per-block partials in d_ws + reduction kernel (no atomics).
// R6: swapped GEMM1 (A=codewords, B=X) -> lane holds all 8 of its k-logits for
//     ONE n: softmax reduce is in-register + 2 shuffles (was 32+4 per wave-iter).
//     exp2-domain logits (log2e folded into u/w). bf16 pack via compiler casts
//     (v_cvt_pk_bf16_f32, ~1 instr/pair vs ~4 manual). NT 256->384: 768 blocks
//     = exactly 3 resident/CU (no tail round), ws 18.9->12.6 MB, reduce 36->24.
#define B_ 32
#define D_ 128
#define K_ 32
#define N_ 9216
#define NT 384      // n per block
#define NCH 24      // N_/NT chunks -> grid 32*24 = 768 = 256 CUs * 3 resident
#define NS 64       // n per sub-chunk
#define XDN_S 72    // X_dn row stride (bf16 shorts) -> 144 B, 16B-aligned
#define AKN_S 72    // A_kn row stride
#define X2S_S 68    // x2 partial stride (floats)
#define L2E 1.4426950408889634f
// X_nd / CWb: stride 128 shorts, 16B-granule XOR swizzle: phys_g = g ^ (row&15)

typedef __bf16 bf16x8_t __attribute__((ext_vector_type(8)));
typedef float f32x4_t __attribute__((ext_vector_type(4)));

__device__ __forceinline__ unsigned short f2bf(float f) {
    return __builtin_bit_cast(unsigned short, (__bf16)f);
}
__device__ __forceinline__ unsigned f2bf_pk(float lo, float hi) {
    return (unsigned)__builtin_bit_cast(unsigned short, (__bf16)lo) |
           ((unsigned)__builtin_bit_cast(unsigned short, (__bf16)hi) << 16);
}
// Barrier that drains LDS only — leaves global (vmcnt) loads in flight.
__device__ __forceinline__ void bar_lds() {
    asm volatile("s_waitcnt lgkmcnt(0)\n\ts_barrier" ::: "memory");
}

__global__ __launch_bounds__(256, 3) void k_fused(
        const float* __restrict__ X, const float* __restrict__ cw,
        const float* __restrict__ scale, float* __restrict__ ws) {
    __shared__ __align__(16) unsigned short X_nd[NS * 128];     // 16384 B (swizzled)
    __shared__ __align__(16) unsigned short X_dn[D_ * XDN_S];   // 18432 B
    __shared__ __align__(16) unsigned short CWb[K_ * 128];      //  8192 B (swizzled)
    __shared__ __align__(16) unsigned short Akn[K_ * AKN_S];    //  4608 B
    __shared__ float x2s[16 * X2S_S];                           //  4352 B
    __shared__ float u_s[K_], w_s[K_];
    __shared__ float sAw[4 * 34];
    __shared__ float sA[K_];

    const int t = threadIdx.x;
    const int w = t >> 6;          // wave 0..3
    const int l = t & 63;          // lane
    const int lm = l & 15;
    const int lq = l >> 4;         // 0..3
    const int d8 = t >> 4;         // staging: d-octet 0..15 (block-spread)
    const int n4 = t & 15;         // staging: n-quad 0..15
    const int b = blockIdx.x / NCH;
    const int n0 = (blockIdx.x % NCH) * NT;

    // ---- stage codewords -> bf16 LDS (swizzled granules) ----
    #pragma unroll
    for (int i = 0; i < 4; ++i) {
        int idx = t + 256 * i;                 // float4 id, 1024 total
        int k = idx >> 5, d4 = idx & 31;
        float4 c = ((const float4*)cw)[idx];
        int phys = (d4 >> 1) ^ (k & 15);
        unsigned* p = (unsigned*)&CWb[k * 128 + phys * 8 + (d4 & 1) * 4];
        p[0] = f2bf_pk(c.x, c.y);
        p[1] = f2bf_pk(c.z, c.w);
    }
    if (t < 32) {
        float sc = scale[t];
        float s2 = sc * sc * L2E;              // exp2-domain scale
        const float4* cr = (const float4*)(cw + t * 128);
        float c2 = 0.f;
        #pragma unroll 8
        for (int i = 0; i < 32; ++i) {
            float4 v = cr[i];
            c2 += v.x * v.x + v.y * v.y + v.z * v.z + v.w * v.w;
        }
        u_s[t] = s2;
        w_s[t] = s2 * c2;
    }
    __syncthreads();
    // lane's 8 k-slots: k = lq*4+r (r=0..3) and 16+lq*4+r (r=4..7)
    float uk[8], wk[8];
    #pragma unroll
    for (int r = 0; r < 4; ++r) {
        uk[r]     = u_s[lq * 4 + r];      wk[r]     = w_s[lq * 4 + r];
        uk[4 + r] = u_s[16 + lq * 4 + r]; wk[4 + r] = w_s[16 + lq * 4 + r];
    }

    f32x4_t acc2[2][2];
    #pragma unroll
    for (int a = 0; a < 2; ++a)
        #pragma unroll
        for (int c = 0; c < 2; ++c)
            acc2[a][c] = (f32x4_t){0.f, 0.f, 0.f, 0.f};
    float ps[8];
    #pragma unroll
    for (int r = 0; r < 8; ++r) ps[r] = 0.f;

    // ---- preload sub-chunk 0: thread owns d = d8*8..+7, n = n0 + n4*4..+3 ----
    const float* Xg = X + ((size_t)b * D_ + d8 * 8) * N_ + n0 + n4 * 4;
    float4 v[8];
    #pragma unroll
    for (int j = 0; j < 8; ++j) v[j] = *(const float4*)(Xg + (size_t)j * N_);

    for (int s = 0; s < 6; ++s) {
        bar_lds();   // B1: prev GEMM2 LDS reads done; restage safe
        // ---- prefetch sub-chunk s+1 (stays in flight across barriers) ----
        float4 vn[8];
        if (s < 5) {
            const float* Xg2 = Xg + (s + 1) * NS;
            #pragma unroll
            for (int j = 0; j < 8; ++j) vn[j] = *(const float4*)(Xg2 + (size_t)j * N_);
        }
        // ---- x2 partials (fp32): sum over this thread's 8 d ----
        {
            float a4[4];
            #pragma unroll
            for (int jn = 0; jn < 4; ++jn) {
                float a = 0.f;
                #pragma unroll
                for (int j = 0; j < 8; ++j) {
                    float xv = (&v[j].x)[jn];
                    a += xv * xv;
                }
                a4[jn] = a;
            }
            *(float4*)&x2s[d8 * X2S_S + n4 * 4] = make_float4(a4[0], a4[1], a4[2], a4[3]);
        }
        // ---- X_dn [d][n_loc] ----
        #pragma unroll
        for (int j = 0; j < 8; ++j) {
            unsigned* p = (unsigned*)&X_dn[(d8 * 8 + j) * XDN_S + n4 * 4];
            p[0] = f2bf_pk(v[j].x, v[j].y);
            p[1] = f2bf_pk(v[j].z, v[j].w);
        }
        // ---- X_nd [n][d], XOR-swizzled granules ----
        #pragma unroll
        for (int jn = 0; jn < 4; ++jn) {
            unsigned q[4];
            #pragma unroll
            for (int j2 = 0; j2 < 4; ++j2)
                q[j2] = f2bf_pk((&v[2 * j2].x)[jn], (&v[2 * j2 + 1].x)[jn]);
            int row = n4 * 4 + jn;
            *(uint4*)&X_nd[row * 128 + ((d8 ^ (row & 15)) * 8)] = *(const uint4*)q;
        }
        bar_lds();   // B2: staging visible to all waves
        // ---- x2 for this lane's n (= w*16+lm): direct column sum, no shuffle ----
        float x2v = 0.f;
        #pragma unroll
        for (int g = 0; g < 16; ++g) x2v += x2s[g * X2S_S + w * 16 + lm];
        // ---- GEMM1 (swapped): D[k][n]; acc1[0] k=lq*4+r, acc1[1] k=16+lq*4+r,
        //      n = w*16+lm (wave w owns n-rows w*16..+15) ----
        f32x4_t acc1[2];
        acc1[0] = (f32x4_t){0.f, 0.f, 0.f, 0.f};
        acc1[1] = (f32x4_t){0.f, 0.f, 0.f, 0.f};
        #pragma unroll
        for (int ks = 0; ks < 4; ++ks) {
            int g = (ks * 4 + lq) ^ lm;    // swizzled granule
            bf16x8_t xb = *(const bf16x8_t*)&X_nd[(w * 16 + lm) * 128 + g * 8];
            bf16x8_t c0 = *(const bf16x8_t*)&CWb[lm * 128 + g * 8];
            bf16x8_t c1 = *(const bf16x8_t*)&CWb[(16 + lm) * 128 + g * 8];
            acc1[0] = __builtin_amdgcn_mfma_f32_16x16x32_bf16(c0, xb, acc1[0], 0, 0, 0);
            acc1[1] = __builtin_amdgcn_mfma_f32_16x16x32_bf16(c1, xb, acc1[1], 0, 0, 0);
        }
        // ---- softmax over k, fully per-lane: 8 logits in-register ----
        float sl[8];
        #pragma unroll
        for (int r = 0; r < 4; ++r) {
            sl[r]     = fmaf(uk[r],     fmaf(acc1[0][r], -2.f, x2v), wk[r]);
            sl[4 + r] = fmaf(uk[4 + r], fmaf(acc1[1][r], -2.f, x2v), wk[4 + r]);
        }
        float m = fmaxf(fmaxf(fmaxf(sl[0], sl[1]), fmaxf(sl[2], sl[3])),
                        fmaxf(fmaxf(sl[4], sl[5]), fmaxf(sl[6], sl[7])));
        m = fmaxf(m, __shfl_xor(m, 16));
        m = fmaxf(m, __shfl_xor(m, 32));
        float p[8], sum = 0.f;
        #pragma unroll
        for (int r = 0; r < 8; ++r) {
            p[r] = __builtin_amdgcn_exp2f(sl[r] - m);   // logits already log2e-scaled
            sum += p[r];
        }
        sum += __shfl_xor(sum, 16);
        sum += __shfl_xor(sum, 32);
        float inv = __builtin_amdgcn_rcpf(sum);
        const int nl = w * 16 + lm;
        #pragma unroll
        for (int r = 0; r < 4; ++r) {
            float p0 = p[r] * inv, p1 = p[4 + r] * inv;
            ps[r] += p0; ps[4 + r] += p1;
            Akn[(lq * 4 + r) * AKN_S + nl]        = f2bf(p0);
            Akn[(16 + lq * 4 + r) * AKN_S + nl]   = f2bf(p1);
        }
        bar_lds();   // B3: Akn visible
        // ---- GEMM2: E[d][k] += X^T[d][n] * A[n][k]; wave w: d-tiles {w, w+4} ----
        #pragma unroll
        for (int ks = 0; ks < 2; ++ks) {
            bf16x8_t xa0 = *(const bf16x8_t*)&X_dn[(w * 16 + lm) * XDN_S + ks * 32 + lq * 8];
            bf16x8_t xa1 = *(const bf16x8_t*)&X_dn[((w + 4) * 16 + lm) * XDN_S + ks * 32 + lq * 8];
            bf16x8_t pb0 = *(const bf16x8_t*)&Akn[lm * AKN_S + ks * 32 + lq * 8];
            bf16x8_t pb1 = *(const bf16x8_t*)&Akn[(16 + lm) * AKN_S + ks * 32 + lq * 8];
            acc2[0][0] = __builtin_amdgcn_mfma_f32_16x16x32_bf16(xa0, pb0, acc2[0][0], 0, 0, 0);
            acc2[0][1] = __builtin_amdgcn_mfma_f32_16x16x32_bf16(xa0, pb1, acc2[0][1], 0, 0, 0);
            acc2[1][0] = __builtin_amdgcn_mfma_f32_16x16x32_bf16(xa1, pb0, acc2[1][0], 0, 0, 0);
            acc2[1][1] = __builtin_amdgcn_mfma_f32_16x16x32_bf16(xa1, pb1, acc2[1][1], 0, 0, 0);
        }
        if (s < 5) {
            #pragma unroll
            for (int j = 0; j < 8; ++j) v[j] = vn[j];
        }
    }

    // ---- block-partial sumA[k]: reduce over the 16 lm lanes (same k-set) ----
    #pragma unroll
    for (int r = 0; r < 8; ++r) {
        ps[r] += __shfl_xor(ps[r], 1);
        ps[r] += __shfl_xor(ps[r], 2);
        ps[r] += __shfl_xor(ps[r], 4);
        ps[r] += __shfl_xor(ps[r], 8);
    }
    __syncthreads();
    if (lm == 0) {
        #pragma unroll
        for (int r = 0; r < 4; ++r) {
            sAw[w * 34 + lq * 4 + r]      = ps[r];
            sAw[w * 34 + 16 + lq * 4 + r] = ps[4 + r];
        }
    }
    __syncthreads();
    if (t < 32) sA[t] = sAw[t] + sAw[34 + t] + sAw[68 + t] + sAw[102 + t];
    __syncthreads();

    // ---- epilogue: per-block partial (E_partial - sumA_partial * c) -> ws ----
    float* pout = ws + (size_t)blockIdx.x * (K_ * D_);
    #pragma unroll
    for (int di = 0; di < 2; ++di) {
        #pragma unroll
        for (int kt = 0; kt < 2; ++kt) {
            const int d0 = (w + di * 4) * 16 + lq * 4;   // C row = M = d
            const int k  = kt * 16 + lm;                 // C col = N = k
            float4 o;
            #pragma unroll
            for (int r = 0; r < 4; ++r)
                (&o.x)[r] = acc2[di][kt][r] - sA[k] * cw[k * 128 + d0 + r];
            *(float4*)&pout[k * 128 + d0] = o;
        }
    }
}

// out[b,k,d] = sum over the 24 block-partials of batch b (deterministic order)
__global__ __launch_bounds__(256) void k_reduce(
        const float* __restrict__ ws, float* __restrict__ out) {
    int i = blockIdx.x * 256 + threadIdx.x;   // float4 index, 0..32767
    int b = i >> 10;                          // 4096/4 = 1024 float4 per batch
    int j = i & 1023;
    const float4* p = (const float4*)ws + (size_t)b * NCH * 1024 + j;
    float4 s = make_float4(0.f, 0.f, 0.f, 0.f);
    #pragma unroll
    for (int c = 0; c < NCH; ++c) {
        float4 v = p[(size_t)c * 1024];
        s.x += v.x; s.y += v.y; s.z += v.z; s.w += v.w;
    }
    ((float4*)out)[i] = s;
}

extern "C" void kernel_launch(void* const* d_in, const int* in_sizes, int n_in,
                              void* d_out, int out_size, void* d_ws, size_t ws_size,
                              hipStream_t stream) {
    const float* X     = (const float*)d_in[0];
    const float* cw    = (const float*)d_in[1];
    const float* scale = (const float*)d_in[2];
    float* out = (float*)d_out;
    float* ws  = (float*)d_ws;     // 768 * 4096 floats = 12.6 MB partials

    k_fused <<<dim3(B_ * NCH), dim3(256), 0, stream>>>(X, cw, scale, ws);
    k_reduce<<<dim3(128),      dim3(256), 0, stream>>>(ws, out);
}